// Round 1
// baseline (319.826 us; speedup 1.0000x reference)
//
#include <hip/hip_runtime.h>
#include <hip/hip_bf16.h>

#define WIN 442
#define HOP 4
#define NBINS 221
#define L_CHUNK 128
#define B2 512          // scan blocks
#define G2 16           // maps per group
#define NG 32           // groups (B2/G2)
#define SPAN 960        // LDS floats per wave (>= 4*(L_CHUNK-1)+446 = 954)

// ---------------- Kernel A: twiddle tables (f64-accurate) ----------------
// TA[a*NBINS+k] = e^{-j*2pi*k*16a/442} as float2 (cos, -sin)
// TBf[k*6+{0..5}] = cos(m*th_k), sin(m*th_k) for m=1,2,3  (f32)
// TBR[k*2+{0,1}]  = cos(4*th_k), sin(4*th_k)              (f64, hop rotation e^{+j4th})
__global__ void k_tables(float2* __restrict__ TA, float* __restrict__ TBf,
                         double* __restrict__ TBR) {
    int idx = blockIdx.x * blockDim.x + threadIdx.x;
    const double TWO_PI = 6.283185307179586476925287;
    if (idx < 28 * NBINS) {
        int a = idx / NBINS, k = idx % NBINS;
        long long t = ((long long)16 * a * k) % WIN;
        double ang = TWO_PI * (double)t / (double)WIN;
        TA[idx] = make_float2((float)cos(ang), (float)(-sin(ang)));
    } else if (idx < 29 * NBINS) {
        int k = idx - 28 * NBINS;
        for (int m = 1; m <= 3; ++m) {
            int t = (m * k) % WIN;
            double ang = TWO_PI * (double)t / (double)WIN;
            TBf[k * 6 + 2 * (m - 1)]     = (float)cos(ang);
            TBf[k * 6 + 2 * (m - 1) + 1] = (float)sin(ang);
        }
        int t4 = (4 * k) % WIN;
        double a4 = TWO_PI * (double)t4 / (double)WIN;
        TBR[k * 2]     = cos(a4);
        TBR[k * 2 + 1] = sin(a4);
    }
}

// ---------------- Kernel B: sliding DFT + per-window argmax ----------------
// One wave per chunk of L_CHUNK windows. 4 bins per lane. f64 accumulator state,
// f64 hop rotation (kills drift), f32 deltas, anchored f32 init with f64 partial sums.
__global__ __launch_bounds__(256) void k_slide(
    const float* __restrict__ x, int n, int n_win, int n_chunks,
    const float2* __restrict__ TA, const float* __restrict__ TBf,
    const double* __restrict__ TBR, int* __restrict__ a_arr) {
    __shared__ __align__(16) float Xs[4][SPAN];
    const int wave = threadIdx.x >> 6;
    const int lane = threadIdx.x & 63;
    const int chunk = blockIdx.x * 4 + wave;
    if (chunk >= n_chunks) return;
    const int w0 = chunk * L_CHUNK;
    const int wend = min(w0 + L_CHUNK, n_win);
    const int s0 = w0 * HOP;
    float* X = Xs[wave];
    // stage chunk samples (wave-private; same-wave LDS ops are HW-ordered, no barrier)
    for (int i = lane; i < SPAN; i += 64) {
        int g = s0 + i;
        X[i] = (g < n) ? x[g] : 0.0f;
    }
    __builtin_amdgcn_wave_barrier();

    int kb[4]; bool act[4];
    float c1[4], s1[4], c2[4], s2[4], c3[4], s3[4];
    double Rr[4], Ri[4];
    double Sr[4] = {0, 0, 0, 0}, Si[4] = {0, 0, 0, 0};
#pragma unroll
    for (int j = 0; j < 4; ++j) {
        int k = lane + 64 * j;
        act[j] = (k < NBINS);
        kb[j] = k;
        int kk = act[j] ? k : (NBINS - 1);
        const float* tb = TBf + kk * 6;
        c1[j] = tb[0]; s1[j] = tb[1];
        c2[j] = tb[2]; s2[j] = tb[3];
        c3[j] = tb[4]; s3[j] = tb[5];
        Rr[j] = TBR[kk * 2]; Ri[j] = TBR[kk * 2 + 1];
    }
    // ---- init DFT for window w0: anchors every 16 samples ----
#pragma unroll 1
    for (int a = 0; a < 27; ++a) {
        int nb = a * 16;
        float pr[4], pi[4], ar[4] = {0, 0, 0, 0}, ai[4] = {0, 0, 0, 0};
#pragma unroll
        for (int j = 0; j < 4; ++j) {
            int kk = act[j] ? kb[j] : (NBINS - 1);
            float2 t = TA[a * NBINS + kk];
            pr[j] = t.x; pi[j] = t.y;
        }
#pragma unroll 4
        for (int q = 0; q < 16; ++q) {
            float xv = X[nb + q];
#pragma unroll
            for (int j = 0; j < 4; ++j) {
                ar[j] = fmaf(xv, pr[j], ar[j]);
                ai[j] = fmaf(xv, pi[j], ai[j]);
                float npr = pr[j] * c1[j] + pi[j] * s1[j];   // p *= e^{-j*th_k}
                pi[j] = pi[j] * c1[j] - pr[j] * s1[j];
                pr[j] = npr;
            }
        }
#pragma unroll
        for (int j = 0; j < 4; ++j) { Sr[j] += (double)ar[j]; Si[j] += (double)ai[j]; }
    }
    {   // tail anchor a=27: n = 432..441
        float pr[4], pi[4], ar[4] = {0, 0, 0, 0}, ai[4] = {0, 0, 0, 0};
#pragma unroll
        for (int j = 0; j < 4; ++j) {
            int kk = act[j] ? kb[j] : (NBINS - 1);
            float2 t = TA[27 * NBINS + kk];
            pr[j] = t.x; pi[j] = t.y;
        }
#pragma unroll 2
        for (int q = 0; q < 10; ++q) {
            float xv = X[432 + q];
#pragma unroll
            for (int j = 0; j < 4; ++j) {
                ar[j] = fmaf(xv, pr[j], ar[j]);
                ai[j] = fmaf(xv, pi[j], ai[j]);
                float npr = pr[j] * c1[j] + pi[j] * s1[j];
                pi[j] = pi[j] * c1[j] - pr[j] * s1[j];
                pr[j] = npr;
            }
        }
#pragma unroll
        for (int j = 0; j < 4; ++j) { Sr[j] += (double)ar[j]; Si[j] += (double)ai[j]; }
    }

    auto emit_argmax = [&](int w) {
        float best = -1.0f; int bi = 0;
#pragma unroll
        for (int j = 0; j < 4; ++j) {
            float m = fabsf((float)Sr[j]) + fabsf((float)Si[j]);
            if (act[j] && m > best) { best = m; bi = kb[j]; }  // j ascending → lowest idx on tie
        }
#pragma unroll
        for (int off = 1; off < 64; off <<= 1) {
            float ov = __shfl_xor(best, off, 64);
            int oi = __shfl_xor(bi, off, 64);
            if (ov > best || (ov == best && oi < bi)) { best = ov; bi = oi; }
        }
        if (lane == 0) a_arr[w] = bi;
    };

    emit_argmax(w0);
    for (int w = w0 + 1; w < wend; ++w) {
        int off = HOP * (w - 1 - w0);
        float d0 = X[off + 442] - X[off];
        float d1 = X[off + 443] - X[off + 1];
        float d2 = X[off + 444] - X[off + 2];
        float d3 = X[off + 445] - X[off + 3];
#pragma unroll
        for (int j = 0; j < 4; ++j) {
            float dr = fmaf(d3, c3[j], fmaf(d2, c2[j], fmaf(d1, c1[j], d0)));
            float di = fmaf(d3, s3[j], fmaf(d2, s2[j], d1 * s1[j]));
            double nr = Sr[j] + (double)dr;
            double ni = Si[j] - (double)di;
            Sr[j] = nr * Rr[j] - ni * Ri[j];   // S *= e^{+j*4th_k}
            Si[j] = nr * Ri[j] + ni * Rr[j];
        }
        emit_argmax(w);
    }
}

// ---------------- Kernel C: per-block scan maps (221-state automaton) ----------------
__global__ void k_maps(const int* __restrict__ a_arr, int n_win, int L2,
                       int2* __restrict__ maps) {
    int j = blockIdx.x;
    int b = threadIdx.x;
    __shared__ int tile[256];
    int w0 = j * L2, wend = min(w0 + L2, n_win);
    float mF = 100.0f * (float)b;
    int bin = b, rw = -1;
    for (int t0 = w0; t0 < wend; t0 += 256) {
        int cnt = min(256, wend - t0);
        if (threadIdx.x < cnt) tile[threadIdx.x] = a_arr[t0 + threadIdx.x];
        __syncthreads();
        for (int i = 0; i < cnt; ++i) {
            int a = tile[i];
            float t = 100.0f * (float)a;
            bool cond = fabsf(mF - t) > mF * 0.0594f;   // exact mirror of reference fp32 op
            if (cond) { mF = t; bin = a; rw = t0 + i; }
        }
        __syncthreads();
    }
    if (b < NBINS) maps[j * NBINS + b] = make_int2(bin, rw);
}

// ---------------- Kernel D1: compose groups of G2 maps into supermaps ----------------
__global__ void k_smaps(const int2* __restrict__ maps, int2* __restrict__ smaps) {
    int g = blockIdx.x;      // 0..NG-1
    int b = threadIdx.x;
    if (b >= NBINS) return;
    int bin = b, rw = -1;
    for (int j = 0; j < G2; ++j) {
        int2 m = maps[(g * G2 + j) * NBINS + bin];
        if (m.y >= 0) { bin = m.x; rw = m.y; }
    }
    smaps[g * NBINS + b] = make_int2(bin, rw);
}

// ---------------- Kernel D2: sequential compose of supermaps + final output ----------------
__global__ void k_compose(const int2* __restrict__ smaps, int2* __restrict__ sentries,
                          float* __restrict__ out_final, int n_win) {
    if (threadIdx.x != 0 || blockIdx.x != 0) return;
    int bin = 0, rw = -1;
    for (int g = 0; g < NG; ++g) {
        sentries[g] = make_int2(bin, rw);
        int2 m = smaps[g * NBINS + bin];
        if (m.y >= 0) { bin = m.x; rw = m.y; }
    }
    float maxF = 100.0f * (float)bin;
    float Ftime = (rw < 0) ? 0.0f : 4.0f * (float)rw;
    float ilast = 4.0f * (float)(n_win - 1);
    out_final[0] = maxF;
    out_final[1] = (ilast - Ftime) * 1000.0f / 44100.0f;
}

// ---------------- Kernel D3: entry state for every scan block ----------------
__global__ void k_entries(const int2* __restrict__ maps, const int2* __restrict__ sentries,
                          int2* __restrict__ entries) {
    int g = blockIdx.x * blockDim.x + threadIdx.x;
    if (g >= NG) return;
    int2 s = sentries[g];
    int bin = s.x, rw = s.y;
    for (int j = 0; j < G2; ++j) {
        entries[g * G2 + j] = make_int2(bin, rw);
        int2 m = maps[(g * G2 + j) * NBINS + bin];
        if (m.y >= 0) { bin = m.x; rw = m.y; }
    }
}

// ---------------- Kernel E: emit flags/freqs/durs ----------------
__global__ void k_emit(const int* __restrict__ a_arr, const int2* __restrict__ entries,
                       int n_win, int L2, float* __restrict__ flags,
                       float* __restrict__ freqs, float* __restrict__ durs) {
    int j = blockIdx.x;
    __shared__ int tile[256];
    int w0 = j * L2, wend = min(w0 + L2, n_win);
    int2 e = entries[j];
    float maxF = 100.0f * (float)e.x;
    float Ftime = (e.y < 0) ? 0.0f : 4.0f * (float)e.y;
    for (int t0 = w0; t0 < wend; t0 += 256) {
        int cnt = min(256, wend - t0);
        if (threadIdx.x < cnt) tile[threadIdx.x] = a_arr[t0 + threadIdx.x];
        __syncthreads();
        if (threadIdx.x == 0) {
            for (int i = 0; i < cnt; ++i) {
                int w = t0 + i;
                float t = 100.0f * (float)tile[i];
                float iw = 4.0f * (float)w;
                bool cond = fabsf(maxF - t) > maxF * 0.0594f;
                flags[w] = cond ? 1.0f : 0.0f;
                freqs[w] = maxF;
                durs[w] = (iw - Ftime) * 1000.0f / 44100.0f;
                if (cond) { maxF = t; Ftime = iw; }
            }
        }
        __syncthreads();
    }
}

extern "C" void kernel_launch(void* const* d_in, const int* in_sizes, int n_in,
                              void* d_out, int out_size, void* d_ws, size_t ws_size,
                              hipStream_t stream) {
    const float* x = (const float*)d_in[0];
    int n = in_sizes[0];
    int n_win = (n - WIN + HOP - 1) / HOP;
    float* out = (float*)d_out;
    char* ws = (char*)d_ws;

    // ws layout (256B-aligned offsets), ~2.03 MB total
    float2* TA       = (float2*)(ws + 0);         // 28*221*8   = 49,504 B
    float*  TBf      = (float*)(ws + 50176);      // 221*6*4    =  5,304 B
    double* TBR      = (double*)(ws + 56320);     // 221*16     =  3,536 B
    int*    a_arr    = (int*)(ws + 60416);        // n_win*4    = 999,560 B
    int2*   maps     = (int2*)(ws + 1060864);     // 512*221*8  = 905,216 B
    int2*   smaps    = (int2*)(ws + 1966080);     // 32*221*8   = 56,576 B
    int2*   sentries = (int2*)(ws + 2022656);     // 32*8
    int2*   entries  = (int2*)(ws + 2022912);     // 512*8

    int n_chunks = (n_win + L_CHUNK - 1) / L_CHUNK;
    int L2 = (n_win + B2 - 1) / B2;

    k_tables<<<dim3((29 * NBINS + 255) / 256), dim3(256), 0, stream>>>(TA, TBf, TBR);
    k_slide<<<dim3((n_chunks + 3) / 4), dim3(256), 0, stream>>>(
        x, n, n_win, n_chunks, TA, TBf, TBR, a_arr);
    k_maps<<<dim3(B2), dim3(256), 0, stream>>>(a_arr, n_win, L2, maps);
    k_smaps<<<dim3(NG), dim3(256), 0, stream>>>(maps, smaps);
    k_compose<<<dim3(1), dim3(64), 0, stream>>>(smaps, sentries,
                                                out + 3 * (size_t)n_win, n_win);
    k_entries<<<dim3(1), dim3(64), 0, stream>>>(maps, sentries, entries);
    k_emit<<<dim3(B2), dim3(256), 0, stream>>>(a_arr, entries, n_win, L2,
                                               out, out + (size_t)n_win,
                                               out + 2 * (size_t)n_win);
}

// Round 3
// 217.229 us; speedup vs baseline: 1.4723x; 1.4723x over previous
//
#include <hip/hip_runtime.h>

#define WIN 442
#define HOP 4
#define NBINS 221
#define LC 128          // windows per chunk
#define SPAN 960        // staged samples per chunk (>= 4*127+446 = 954)
#define B2 1024         // scan segments

// ---------------- Kernel A: twiddle tables ----------------
// g_tab[t] = omega^t = e^{-j*2pi*t/442}, f32 (cos, -sin)
// TBR[k]   = (cos(4*th_k), +sin(4*th_k)), f64  (slide rotation e^{+j4th})
__global__ void k_tables(float2* __restrict__ g_tab, double2* __restrict__ TBR) {
    int t = blockIdx.x * blockDim.x + threadIdx.x;
    const double TWO_PI = 6.283185307179586476925287;
    if (t < WIN) {
        double ang = TWO_PI * (double)t / (double)WIN;
        g_tab[t] = make_float2((float)cos(ang), (float)(-sin(ang)));
    }
    if (t < NBINS) {
        int t4 = (4 * t) % WIN;
        double a4 = TWO_PI * (double)t4 / (double)WIN;
        TBR[t] = make_double2(cos(a4), sin(a4));
    }
}

// ---------------- Kernel B: sliding DFT (f64 state, R1-exact) + argmax ----------------
// Block = 4 waves = 2 chunks; 2 waves per chunk, 2 bins/lane.
// Init: f64 Horner over 4-sample f32 groups, descending t:  V <- V*omega^{4k} + D_t
//       (seed = x440 + x441*omega^k), giving S_0 = sum x_m omega^{km} exactly-in-f64
//       up to f32 group rounding (~3e-6).
// Slide: S' = e^{+j4th}(S + Delta), Delta in f32 -> f64, rotation f64 (zero drift).
__global__ __launch_bounds__(256) void k_slide(
    const float* __restrict__ x, int n, int n_win, int n_chunks,
    const float2* __restrict__ g_tab, const double2* __restrict__ TBRg,
    int* __restrict__ a_arr) {
    __shared__ float2 tab[WIN];
    __shared__ __align__(16) float Xs[2][SPAN];
    __shared__ float4 Ds[2][LC];
    __shared__ float candm[2][LC][8];
    __shared__ int   candk[2][LC][8];

    const int tid = threadIdx.x;
    const int lane = tid & 63;
    const int wv = tid >> 6;     // 0..3
    const int c = wv >> 1;       // chunk slot
    const int wc = wv & 1;       // bin half
    const int chunk = blockIdx.x * 2 + c;

    for (int t = tid; t < WIN; t += 256) tab[t] = g_tab[t];
    const int base = blockIdx.x * 1024;      // samples; chunk stride = 512
    for (int i = tid; i < 2 * SPAN; i += 256) {
        int cc = (i < SPAN) ? 0 : 1;
        int o = (i < SPAN) ? i : i - SPAN;
        int g = base + cc * 512 + o;
        Xs[cc][o] = (g < n) ? x[g] : 0.0f;
    }
    __syncthreads();
    for (int i = tid; i < 2 * LC * 4; i += 256) {   // D[w][p] = X[4w+442+p]-X[4w+p]
        int cc = i >> 9, r = i & 511;
        ((float*)Ds)[cc * 512 + r] = Xs[cc][r + WIN] - Xs[cc][r];
    }
    __syncthreads();

    const bool valid = (chunk < n_chunks);
    const int wlen = valid ? min(LC, n_win - chunk * LC) : 0;

    // per-lane bins: wc=0 -> k = lane, lane+64 ; wc=1 -> lane+128, lane+192
    const int k0 = lane + 128 * wc, k1 = k0 + 64;
    const bool a0 = (k0 < NBINS), a1 = (k1 < NBINS);
    const int kk0 = a0 ? k0 : 0, kk1 = a1 ? k1 : 0;
    const float2 e1_0 = tab[kk0], e1_1 = tab[kk1];          // omega^k  (cos, -sin)
    const float2 e2_0 = tab[2 * kk0], e2_1 = tab[2 * kk1];  // 2k <= 440
    int t3 = 3 * kk0; if (t3 >= WIN) t3 -= WIN; const float2 e3_0 = tab[t3];
    t3 = 3 * kk1; if (t3 >= WIN) t3 -= WIN; const float2 e3_1 = tab[t3];
    const double2 Rk0 = TBRg[kk0], Rk1 = TBRg[kk1];         // (cos4th, +sin4th) f64

    double S0r = 0.0, S0i = 0.0, S1r = 0.0, S1i = 0.0;

    auto emitw = [&](int w) {
        float m0 = a0 ? (fabsf((float)S0r) + fabsf((float)S0i)) : -1.0f;
        float m1 = a1 ? (fabsf((float)S1r) + fabsf((float)S1i)) : -1.0f;
        float m = m0; int kb = k0;
        if (m1 > m) { m = m1; kb = k1; }           // tie -> keep lower k (k0<k1)
#pragma unroll
        for (int off = 32; off >= 4; off >>= 1) {  // leaves classes (lane mod 4)
            float om = __shfl_xor(m, off, 64);
            int ok = __shfl_xor(kb, off, 64);
            if (om > m || (om == m && ok < kb)) { m = om; kb = ok; }
        }
        if (lane < 4) { candm[c][w][wc * 4 + lane] = m; candk[c][w][wc * 4 + lane] = kb; }
    };

    if (valid) {
        // ---- init: f64 Horner, descending 4-sample groups; V *= (Rr, -Ri); V += D ----
        {
            float xa = Xs[c][440], xb = Xs[c][441];
            S0r = (double)fmaf(xb, e1_0.x, xa);
            S0i = (double)(xb * e1_0.y);
            S1r = (double)fmaf(xb, e1_1.x, xa);
            S1i = (double)(xb * e1_1.y);
            const float4* Xq = (const float4*)Xs[c];
#pragma unroll 2
            for (int t = 109; t >= 0; --t) {
                float4 xv = Xq[t];
                float Dr0 = fmaf(xv.w, e3_0.x, fmaf(xv.z, e2_0.x, fmaf(xv.y, e1_0.x, xv.x)));
                float Di0 = fmaf(xv.w, e3_0.y, fmaf(xv.z, e2_0.y, xv.y * e1_0.y));
                double nr = fma(S0i, Rk0.y, fma(S0r, Rk0.x, (double)Dr0));   // Vr*Rr+Vi*Ri+Dr
                double ni = fma(-S0r, Rk0.y, fma(S0i, Rk0.x, (double)Di0));  // Vi*Rr-Vr*Ri+Di
                S0r = nr; S0i = ni;
                float Dr1 = fmaf(xv.w, e3_1.x, fmaf(xv.z, e2_1.x, fmaf(xv.y, e1_1.x, xv.x)));
                float Di1 = fmaf(xv.w, e3_1.y, fmaf(xv.z, e2_1.y, xv.y * e1_1.y));
                nr = fma(S1i, Rk1.y, fma(S1r, Rk1.x, (double)Dr1));
                ni = fma(-S1r, Rk1.y, fma(S1i, Rk1.x, (double)Di1));
                S1r = nr; S1i = ni;
            }
        }
        emitw(0);

        // ---- slide: S' = (S + Delta) * e^{+j4th} ----
        const float4* Dq = (const float4*)Ds[c];
        for (int it = 0; it < wlen - 1; ++it) {
            float4 d = Dq[it];
            float Dr0 = fmaf(d.w, e3_0.x, fmaf(d.z, e2_0.x, fmaf(d.y, e1_0.x, d.x)));
            float Di0 = fmaf(d.w, e3_0.y, fmaf(d.z, e2_0.y, d.y * e1_0.y));
            double nr = S0r + (double)Dr0;
            double ni = S0i + (double)Di0;
            S0r = fma(nr, Rk0.x, -(ni * Rk0.y));   // nr*Rr - ni*Ri
            S0i = fma(nr, Rk0.y, ni * Rk0.x);      // nr*Ri + ni*Rr
            float Dr1 = fmaf(d.w, e3_1.x, fmaf(d.z, e2_1.x, fmaf(d.y, e1_1.x, d.x)));
            float Di1 = fmaf(d.w, e3_1.y, fmaf(d.z, e2_1.y, d.y * e1_1.y));
            nr = S1r + (double)Dr1;
            ni = S1i + (double)Di1;
            S1r = fma(nr, Rk1.x, -(ni * Rk1.y));
            S1i = fma(nr, Rk1.y, ni * Rk1.x);
            emitw(it + 1);
        }
    }
    __syncthreads();
    // ---- merge 8 candidates per window ----
    {
        int c2 = tid >> 7, w = tid & 127;
        int ch = blockIdx.x * 2 + c2;
        if (ch < n_chunks) {
            int wl = min(LC, n_win - ch * LC);
            if (w < wl) {
                float bm = -2.0f; int bk = 0;
#pragma unroll
                for (int i = 0; i < 8; ++i) {
                    float mi = candm[c2][w][i]; int ki = candk[c2][w][i];
                    if (mi > bm || (mi == bm && ki < bk)) { bm = mi; bk = ki; }
                }
                a_arr[ch * LC + w] = bk;
            }
        }
    }
}

// ---------------- Kernel C: per-segment automaton maps, packed (rw+1)<<8 | bin ----------------
__global__ __launch_bounds__(256) void k_maps(const int* __restrict__ a_arr, int n_win,
                                              int L2, int* __restrict__ M0) {
    __shared__ float tf[512];
    __shared__ int ti[512];
    int j = blockIdx.x;
    int wbeg = j * L2;
    int cnt = n_win - wbeg; if (cnt > L2) cnt = L2; if (cnt < 0) cnt = 0;
    for (int i = threadIdx.x; i < cnt; i += 256) {
        int a = a_arr[wbeg + i];
        ti[i] = a; tf[i] = 100.0f * (float)a;
    }
    __syncthreads();
    int b = threadIdx.x;
    if (b < NBINS) {
        float mF = 100.0f * (float)b;
        int bin = b, rw = -1;
        for (int i = 0; i < cnt; ++i) {
            float t = tf[i];
            if (fabsf(mF - t) > mF * 0.0594f) { mF = t; bin = ti[i]; rw = wbeg + i; }
        }
        M0[j * NBINS + b] = ((rw + 1) << 8) | bin;
    }
}

// ---------------- Kernel D: compose 32 consecutive M0 -> M1 (32 groups) ----------------
__global__ void k_sm1(const int* __restrict__ M0, int* __restrict__ M1) {
    int g = blockIdx.x, b = threadIdx.x;
    if (b >= NBINS) return;
    int bin = b, rw = -1;
    for (int i = 0; i < 32; ++i) {
        int mp = M0[(g * 32 + i) * NBINS + bin];
        if (mp >> 8) { rw = (mp >> 8) - 1; bin = mp & 255; }
    }
    M1[g * NBINS + b] = ((rw + 1) << 8) | bin;
}

// ---------------- Kernel E: group entries E1 + final output ----------------
__global__ void k_top(const int* __restrict__ M1, int* __restrict__ E1,
                      float* __restrict__ out_final, int n_win) {
    if (threadIdx.x != 0 || blockIdx.x != 0) return;
    int bin = 0, rw = -1;
    for (int g = 0; g < 32; ++g) {
        E1[g] = ((rw + 1) << 8) | bin;
        int mp = M1[g * NBINS + bin];
        if (mp >> 8) { rw = (mp >> 8) - 1; bin = mp & 255; }
    }
    float maxF = 100.0f * (float)bin;
    float Ftime = (rw < 0) ? 0.0f : 4.0f * (float)rw;
    float ilast = 4.0f * (float)(n_win - 1);
    out_final[0] = maxF;
    out_final[1] = (ilast - Ftime) * 1000.0f / 44100.0f;
}

// ---------------- Kernel F: per-segment entries E0 ----------------
__global__ void k_e0(const int* __restrict__ M0, const int* __restrict__ E1,
                     int* __restrict__ E0) {
    int j = blockIdx.x * 256 + threadIdx.x;
    if (j >= B2) return;
    int g = j >> 5;
    int st = E1[g];
    int bin = st & 255, rw = (st >> 8) - 1;
    for (int i = g * 32; i < j; ++i) {
        int mp = M0[i * NBINS + bin];
        if (mp >> 8) { rw = (mp >> 8) - 1; bin = mp & 255; }
    }
    E0[j] = ((rw + 1) << 8) | bin;
}

// ---------------- Kernel G: emit flags/freqs/durs (thread-per-window rescan) ----------------
__global__ __launch_bounds__(256) void k_emit(const int* __restrict__ a_arr,
    const int* __restrict__ E0, int n_win, int L2,
    float* __restrict__ flags, float* __restrict__ freqs, float* __restrict__ durs) {
    __shared__ float tf[512];
    int j = blockIdx.x;
    int wbeg = j * L2;
    int cnt = n_win - wbeg; if (cnt > L2) cnt = L2;
    if (cnt <= 0) return;
    for (int i = threadIdx.x; i < cnt; i += 256) tf[i] = 100.0f * (float)a_arr[wbeg + i];
    __syncthreads();
    int t = threadIdx.x;
    if (t < cnt) {
        int st = E0[j];
        float maxF = 100.0f * (float)(st & 255);
        int rw = (st >> 8) - 1;
        float Ftime = (rw < 0) ? 0.0f : 4.0f * (float)rw;
        for (int i = 0; i < t; ++i) {
            float tv = tf[i];
            if (fabsf(maxF - tv) > maxF * 0.0594f) {
                maxF = tv; Ftime = 4.0f * (float)(wbeg + i);
            }
        }
        int w = wbeg + t;
        float tv = tf[t];
        float iw = 4.0f * (float)w;
        bool cond = fabsf(maxF - tv) > maxF * 0.0594f;
        flags[w] = cond ? 1.0f : 0.0f;
        freqs[w] = maxF;
        durs[w] = (iw - Ftime) * 1000.0f / 44100.0f;
    }
}

extern "C" void kernel_launch(void* const* d_in, const int* in_sizes, int n_in,
                              void* d_out, int out_size, void* d_ws, size_t ws_size,
                              hipStream_t stream) {
    const float* x = (const float*)d_in[0];
    int n = in_sizes[0];
    int n_win = (n - WIN + HOP - 1) / HOP;
    float* out = (float*)d_out;
    char* ws = (char*)d_ws;

    // ws layout (~1.95 MB)
    float2*  g_tab = (float2*)(ws + 0);          //   3,536 B
    double2* TBR   = (double2*)(ws + 4096);      //   3,536 B
    int* a_arr     = (int*)(ws + 8192);          // 999,560 B
    int* M0        = (int*)(ws + 1007872);       // 905,216 B
    int* M1        = (int*)(ws + 1913088);       //  28,288 B
    int* E1        = (int*)(ws + 1941504);       //     128 B
    int* E0        = (int*)(ws + 1941760);       //   4,096 B

    int n_chunks = (n_win + LC - 1) / LC;
    int slide_blocks = (n_chunks + 1) / 2;
    int L2 = (n_win + B2 - 1) / B2;

    k_tables<<<dim3(2), dim3(256), 0, stream>>>(g_tab, TBR);
    k_slide<<<dim3(slide_blocks), dim3(256), 0, stream>>>(x, n, n_win, n_chunks,
                                                          g_tab, TBR, a_arr);
    k_maps<<<dim3(B2), dim3(256), 0, stream>>>(a_arr, n_win, L2, M0);
    k_sm1<<<dim3(32), dim3(256), 0, stream>>>(M0, M1);
    k_top<<<dim3(1), dim3(64), 0, stream>>>(M1, E1, out + 3 * (size_t)n_win, n_win);
    k_e0<<<dim3(4), dim3(256), 0, stream>>>(M0, E1, E0);
    k_emit<<<dim3(B2), dim3(256), 0, stream>>>(a_arr, E0, n_win, L2,
                                               out, out + (size_t)n_win,
                                               out + 2 * (size_t)n_win);
}

// Round 4
// 198.772 us; speedup vs baseline: 1.6090x; 1.0929x over previous
//
#include <hip/hip_runtime.h>

#define WIN 442
#define HOP 4
#define NBINS 221
#define LC 128          // windows per chunk
#define SPAN 960        // staged samples per chunk (>= 4*127+446 = 954)
#define B2 1024         // scan segments
#define NG 32           // map groups (B2/32)

// ---------------- Kernel A: twiddle tables ----------------
// g_tab[t] = omega^t = e^{-j*2pi*t/442}, f32 (cos, -sin)
// TBR[k]   = (cos(4*th_k), +sin(4*th_k)), f64  (slide rotation e^{+j4th})
__global__ void k_tables(float2* __restrict__ g_tab, double2* __restrict__ TBR) {
    int t = blockIdx.x * blockDim.x + threadIdx.x;
    const double TWO_PI = 6.283185307179586476925287;
    if (t < WIN) {
        double ang = TWO_PI * (double)t / (double)WIN;
        g_tab[t] = make_float2((float)cos(ang), (float)(-sin(ang)));
    }
    if (t < NBINS) {
        int t4 = (4 * t) % WIN;
        double a4 = TWO_PI * (double)t4 / (double)WIN;
        TBR[t] = make_double2(cos(a4), sin(a4));
    }
}

// ---------------- Kernel B: sliding DFT (f64 state) + batched argmax ----------------
// 1 chunk per 128-thread block (2 waves, 2 bins/lane). Numerics identical to R3
// (f64 Horner init descending; slide S' = (S+Delta)*e^{+j4th} in f64).
// Argmax: per-window (m,k) gathered for 16 windows in registers, then 16
// independent interleaved butterflies (off 32..4) -> 8 candidates/window in LDS.
__global__ __launch_bounds__(128) void k_slide(
    const float* __restrict__ x, int n, int n_win, int n_chunks,
    const float2* __restrict__ g_tab, const double2* __restrict__ TBRg,
    int* __restrict__ a_arr) {
    __shared__ float2 tab[WIN];
    __shared__ __align__(16) float Xs[SPAN];
    __shared__ __align__(16) float Ds_[LC * 4];
    __shared__ float candm[LC][8];
    __shared__ int   candk[LC][8];

    const int tid = threadIdx.x;
    const int lane = tid & 63;
    const int wc = tid >> 6;                 // bin half (2 waves)
    const int chunk = blockIdx.x;
    const int s0 = chunk * (LC * HOP);

    for (int t = tid; t < WIN; t += 128) tab[t] = g_tab[t];
    for (int i = tid; i < SPAN; i += 128) {
        int g = s0 + i;
        Xs[i] = (g < n) ? x[g] : 0.0f;
    }
    __syncthreads();
    for (int r = tid; r < LC * 4; r += 128) Ds_[r] = Xs[r + WIN] - Xs[r];
    __syncthreads();

    const int wlen = min(LC, n_win - chunk * LC);

    // per-lane bins: wc=0 -> k = lane, lane+64 ; wc=1 -> lane+128, lane+192
    const int k0 = lane + 128 * wc, k1 = k0 + 64;
    const bool a0 = (k0 < NBINS), a1 = (k1 < NBINS);
    const int kk0 = a0 ? k0 : 0, kk1 = a1 ? k1 : 0;
    const float2 e1_0 = tab[kk0], e1_1 = tab[kk1];          // omega^k  (cos, -sin)
    const float2 e2_0 = tab[2 * kk0], e2_1 = tab[2 * kk1];  // 2k <= 440
    int t3 = 3 * kk0; if (t3 >= WIN) t3 -= WIN; const float2 e3_0 = tab[t3];
    t3 = 3 * kk1; if (t3 >= WIN) t3 -= WIN; const float2 e3_1 = tab[t3];
    const double2 Rk0 = TBRg[kk0], Rk1 = TBRg[kk1];         // (cos4th, +sin4th) f64

    double S0r, S0i, S1r, S1i;
    // ---- init: f64 Horner, descending 4-sample groups; V <- V*omega^{4k} + D_t ----
    {
        float xa = Xs[440], xb = Xs[441];
        S0r = (double)fmaf(xb, e1_0.x, xa);
        S0i = (double)(xb * e1_0.y);
        S1r = (double)fmaf(xb, e1_1.x, xa);
        S1i = (double)(xb * e1_1.y);
        const float4* Xq = (const float4*)Xs;
#pragma unroll 2
        for (int t = 109; t >= 0; --t) {
            float4 xv = Xq[t];
            float Dr0 = fmaf(xv.w, e3_0.x, fmaf(xv.z, e2_0.x, fmaf(xv.y, e1_0.x, xv.x)));
            float Di0 = fmaf(xv.w, e3_0.y, fmaf(xv.z, e2_0.y, xv.y * e1_0.y));
            double nr = fma(S0i, Rk0.y, fma(S0r, Rk0.x, (double)Dr0));   // Vr*Rr+Vi*Ri+Dr
            double ni = fma(-S0r, Rk0.y, fma(S0i, Rk0.x, (double)Di0));  // Vi*Rr-Vr*Ri+Di
            S0r = nr; S0i = ni;
            float Dr1 = fmaf(xv.w, e3_1.x, fmaf(xv.z, e2_1.x, fmaf(xv.y, e1_1.x, xv.x)));
            float Di1 = fmaf(xv.w, e3_1.y, fmaf(xv.z, e2_1.y, xv.y * e1_1.y));
            nr = fma(S1i, Rk1.y, fma(S1r, Rk1.x, (double)Dr1));
            ni = fma(-S1r, Rk1.y, fma(S1i, Rk1.x, (double)Di1));
            S1r = nr; S1i = ni;
        }
    }

    const float4* Dq = (const float4*)Ds_;
    for (int b = 0; b < 8; ++b) {            // 8 batches x 16 windows
        float mm[16]; int kk[16];
#pragma unroll
        for (int u = 0; u < 16; ++u) {
            if (b | u) {                     // slide into window b*16+u
                float4 d = Dq[b * 16 + u - 1];
                float Dr0 = fmaf(d.w, e3_0.x, fmaf(d.z, e2_0.x, fmaf(d.y, e1_0.x, d.x)));
                float Di0 = fmaf(d.w, e3_0.y, fmaf(d.z, e2_0.y, d.y * e1_0.y));
                double nr = S0r + (double)Dr0;
                double ni = S0i + (double)Di0;
                S0r = fma(nr, Rk0.x, -(ni * Rk0.y));   // nr*Rr - ni*Ri
                S0i = fma(nr, Rk0.y, ni * Rk0.x);      // nr*Ri + ni*Rr
                float Dr1 = fmaf(d.w, e3_1.x, fmaf(d.z, e2_1.x, fmaf(d.y, e1_1.x, d.x)));
                float Di1 = fmaf(d.w, e3_1.y, fmaf(d.z, e2_1.y, d.y * e1_1.y));
                nr = S1r + (double)Dr1;
                ni = S1i + (double)Di1;
                S1r = fma(nr, Rk1.x, -(ni * Rk1.y));
                S1i = fma(nr, Rk1.y, ni * Rk1.x);
            }
            float m0 = a0 ? (fabsf((float)S0r) + fabsf((float)S0i)) : -1.0f;
            float m1 = a1 ? (fabsf((float)S1r) + fabsf((float)S1i)) : -1.0f;
            float m = m0; int kb = k0;
            if (m1 > m) { m = m1; kb = k1; }           // tie -> lower k (k0<k1)
            mm[u] = m; kk[u] = kb;
        }
        // ---- 16 interleaved butterflies, stages 32,16,8,4 ----
#pragma unroll
        for (int s = 0; s < 4; ++s) {
            const int off = 32 >> s;
#pragma unroll
            for (int u = 0; u < 16; ++u) {
                float om = __shfl_xor(mm[u], off, 64);
                int ok = __shfl_xor(kk[u], off, 64);
                if (om > mm[u] || (om == mm[u] && ok < kk[u])) { mm[u] = om; kk[u] = ok; }
            }
        }
        if (lane < 4) {
#pragma unroll
            for (int u = 0; u < 16; ++u) {
                candm[b * 16 + u][wc * 4 + lane] = mm[u];
                candk[b * 16 + u][wc * 4 + lane] = kk[u];
            }
        }
    }
    __syncthreads();
    // ---- merge 8 candidates per window ----
    if (tid < wlen) {
        float bm = -2.0f; int bk = 0;
#pragma unroll
        for (int i = 0; i < 8; ++i) {
            float mi = candm[tid][i]; int ki = candk[tid][i];
            if (mi > bm || (mi == bm && ki < bk)) { bm = mi; bk = ki; }
        }
        a_arr[chunk * LC + tid] = bk;
    }
}

// ---------------- Kernel C: per-segment automaton maps, packed (rw+1)<<8 | bin ----------------
__global__ __launch_bounds__(256) void k_maps(const int* __restrict__ a_arr, int n_win,
                                              int L2, int* __restrict__ M0) {
    __shared__ float tf[256];
    __shared__ int ti[256];
    int j = blockIdx.x;
    int wbeg = j * L2;
    int cnt = n_win - wbeg; if (cnt > L2) cnt = L2; if (cnt < 0) cnt = 0;
    for (int i = threadIdx.x; i < cnt; i += 256) {
        int a = a_arr[wbeg + i];
        ti[i] = a; tf[i] = 100.0f * (float)a;
    }
    __syncthreads();
    int b = threadIdx.x;
    if (b < NBINS) {
        float mF = 100.0f * (float)b;
        int bin = b, rw = -1;
        for (int i = 0; i < cnt; ++i) {
            float t = tf[i];
            if (fabsf(mF - t) > mF * 0.0594f) { mF = t; bin = ti[i]; rw = wbeg + i; }
        }
        M0[j * NBINS + b] = ((rw + 1) << 8) | bin;
    }
}

// ---------------- Kernel D: compose 32 consecutive M0 -> M1, LDS-staged ----------------
__global__ __launch_bounds__(256) void k_sm1(const int* __restrict__ M0,
                                             int* __restrict__ M1) {
    __shared__ int sm[32 * NBINS];
    int g = blockIdx.x;
    for (int i = threadIdx.x; i < 32 * NBINS; i += 256) sm[i] = M0[g * 32 * NBINS + i];
    __syncthreads();
    int b = threadIdx.x;
    if (b < NBINS) {
        int bin = b, rw = -1;
        for (int i = 0; i < 32; ++i) {
            int mp = sm[i * NBINS + bin];
            if (mp >> 8) { rw = (mp >> 8) - 1; bin = mp & 255; }
        }
        M1[g * NBINS + b] = ((rw + 1) << 8) | bin;
    }
}

// ---------------- Kernel E: per-segment entries E0, LDS-staged (E1 recomputed per block) ----------------
__global__ __launch_bounds__(256) void k_e0(const int* __restrict__ M0,
                                            const int* __restrict__ M1,
                                            int* __restrict__ E0) {
    __shared__ int sm1[NG * NBINS];     // all M1
    __shared__ int sm0[32 * NBINS];     // this group's M0 rows
    int g = blockIdx.x;
    for (int i = threadIdx.x; i < NG * NBINS; i += 256) sm1[i] = M1[i];
    for (int i = threadIdx.x; i < 32 * NBINS; i += 256) sm0[i] = M0[g * 32 * NBINS + i];
    __syncthreads();
    int j = threadIdx.x;
    if (j < 32) {
        int bin = 0, rw = -1;
        for (int i = 0; i < g; ++i) {               // E1[g]: chain M1[0..g)
            int mp = sm1[i * NBINS + bin];
            if (mp >> 8) { rw = (mp >> 8) - 1; bin = mp & 255; }
        }
        for (int i = 0; i < j; ++i) {               // chain this group's M0[0..j)
            int mp = sm0[i * NBINS + bin];
            if (mp >> 8) { rw = (mp >> 8) - 1; bin = mp & 255; }
        }
        E0[g * 32 + j] = ((rw + 1) << 8) | bin;
    }
}

// ---------------- Kernel F: emit flags/freqs/durs + final (thread-per-window rescan) ----------------
__global__ __launch_bounds__(256) void k_emit(const int* __restrict__ a_arr,
    const int* __restrict__ E0, int n_win, int L2,
    float* __restrict__ flags, float* __restrict__ freqs, float* __restrict__ durs,
    float* __restrict__ out_final) {
    __shared__ float tf[256];
    int j = blockIdx.x;
    int wbeg = j * L2;
    int cnt = n_win - wbeg; if (cnt > L2) cnt = L2;
    if (cnt <= 0) return;
    for (int i = threadIdx.x; i < cnt; i += 256) tf[i] = 100.0f * (float)a_arr[wbeg + i];
    __syncthreads();
    int t = threadIdx.x;
    if (t < cnt) {
        int st = E0[j];
        float maxF = 100.0f * (float)(st & 255);
        int rw = (st >> 8) - 1;
        float Ftime = (rw < 0) ? 0.0f : 4.0f * (float)rw;
        for (int i = 0; i < t; ++i) {
            float tv = tf[i];
            if (fabsf(maxF - tv) > maxF * 0.0594f) {
                maxF = tv; Ftime = 4.0f * (float)(wbeg + i);
            }
        }
        int w = wbeg + t;
        float tv = tf[t];
        float iw = 4.0f * (float)w;
        bool cond = fabsf(maxF - tv) > maxF * 0.0594f;
        flags[w] = cond ? 1.0f : 0.0f;
        freqs[w] = maxF;
        durs[w] = (iw - Ftime) * 1000.0f / 44100.0f;
        if (w == n_win - 1) {                       // fold final-state output here
            float fMax = cond ? tv : maxF;
            float fT   = cond ? iw : Ftime;
            out_final[0] = fMax;
            out_final[1] = (iw - fT) * 1000.0f / 44100.0f;
        }
    }
}

extern "C" void kernel_launch(void* const* d_in, const int* in_sizes, int n_in,
                              void* d_out, int out_size, void* d_ws, size_t ws_size,
                              hipStream_t stream) {
    const float* x = (const float*)d_in[0];
    int n = in_sizes[0];
    int n_win = (n - WIN + HOP - 1) / HOP;
    float* out = (float*)d_out;
    char* ws = (char*)d_ws;

    int n_chunks = (n_win + LC - 1) / LC;
    int L2 = (n_win + B2 - 1) / B2;

    // ws layout (~1.95 MB)
    float2*  g_tab = (float2*)(ws + 0);          //   3,536 B
    double2* TBR   = (double2*)(ws + 4096);      //   3,536 B
    int* a_arr     = (int*)(ws + 8192);          // n_chunks*128*4 = 999,936 B
    int* M0        = (int*)(ws + 1008640);       // 1024*221*4 = 905,216 B
    int* M1        = (int*)(ws + 1914112);       //  28,288 B
    int* E0        = (int*)(ws + 1942528);       //   4,096 B

    k_tables<<<dim3(2), dim3(256), 0, stream>>>(g_tab, TBR);
    k_slide<<<dim3(n_chunks), dim3(128), 0, stream>>>(x, n, n_win, n_chunks,
                                                      g_tab, TBR, a_arr);
    k_maps<<<dim3(B2), dim3(256), 0, stream>>>(a_arr, n_win, L2, M0);
    k_sm1<<<dim3(NG), dim3(256), 0, stream>>>(M0, M1);
    k_e0<<<dim3(NG), dim3(256), 0, stream>>>(M0, M1, E0);
    k_emit<<<dim3(B2), dim3(256), 0, stream>>>(a_arr, E0, n_win, L2,
                                               out, out + (size_t)n_win,
                                               out + 2 * (size_t)n_win,
                                               out + 3 * (size_t)n_win);
}

// Round 5
// 178.300 us; speedup vs baseline: 1.7938x; 1.1148x over previous
//
#include <hip/hip_runtime.h>

#define WIN 442
#define HOP 4
#define NBINS 221
#define LC 128          // windows per chunk
#define SPAN 960        // staged samples per chunk (>= 4*127+446 = 954)
#define B2 1024         // scan segments
#define NG 32           // map groups (B2/32)

// 64-bit xor-shuffle (reg-pair; compiler folds the pack/unpack)
static __device__ __forceinline__ unsigned long long shflx64(unsigned long long v, int off) {
    unsigned int lo = (unsigned int)v, hi = (unsigned int)(v >> 32);
    lo = __shfl_xor(lo, off, 64);
    hi = __shfl_xor(hi, off, 64);
    return ((unsigned long long)hi << 32) | lo;
}

// ---------------- Kernel A: twiddle tables ----------------
// g_tab[t] = omega^t = e^{-j*2pi*t/442}, f32 (cos, -sin)
// TBR[k]   = (cos(4*th_k), +sin(4*th_k)), f64  (slide rotation e^{+j4th})
__global__ void k_tables(float2* __restrict__ g_tab, double2* __restrict__ TBR) {
    int t = blockIdx.x * blockDim.x + threadIdx.x;
    const double TWO_PI = 6.283185307179586476925287;
    if (t < WIN) {
        double ang = TWO_PI * (double)t / (double)WIN;
        g_tab[t] = make_float2((float)cos(ang), (float)(-sin(ang)));
    }
    if (t < NBINS) {
        int t4 = (4 * t) % WIN;
        double a4 = TWO_PI * (double)t4 / (double)WIN;
        TBR[t] = make_double2(cos(a4), sin(a4));
    }
}

// ---------------- Kernel B: sliding DFT (f64 state) + u64-key argmax ----------------
// 1 chunk per 128-thread block (2 waves, 2 bins/lane). Slide/init numerics identical
// to R3/R4 (f64 Horner init descending; S' = (S+Delta)*e^{+j4th} in f64).
// Argmax key = (f32 mag bits << 32) | (255-k): single u64 compare gives
// mag-compare with exact lowest-index tie-break. Inactive bins: Rk=0 & S=0 -> mag 0.
__global__ __launch_bounds__(128) void k_slide(
    const float* __restrict__ x, int n, int n_win, int n_chunks,
    const float2* __restrict__ g_tab, const double2* __restrict__ TBRg,
    int* __restrict__ a_arr) {
    __shared__ float2 tab[WIN];
    __shared__ __align__(16) float Xs[SPAN];
    __shared__ __align__(16) float Ds_[LC * 4];
    __shared__ unsigned long long cand[LC][9];   // [8] used; pad breaks bank aliasing

    const int tid = threadIdx.x;
    const int lane = tid & 63;
    const int wc = tid >> 6;                 // bin half (2 waves)
    const int chunk = blockIdx.x;
    const int s0 = chunk * (LC * HOP);

    for (int t = tid; t < WIN; t += 128) tab[t] = g_tab[t];
    for (int i = tid; i < SPAN; i += 128) {
        int g = s0 + i;
        Xs[i] = (g < n) ? x[g] : 0.0f;
    }
    __syncthreads();
    for (int r = tid; r < LC * 4; r += 128) Ds_[r] = Xs[r + WIN] - Xs[r];
    __syncthreads();

    const int wlen = min(LC, n_win - chunk * LC);

    // per-lane bins: wc=0 -> k = lane, lane+64 ; wc=1 -> lane+128, lane+192
    const int k0 = lane + 128 * wc, k1 = k0 + 64;
    const bool a0 = (k0 < NBINS), a1 = (k1 < NBINS);
    const int kk0 = a0 ? k0 : 0, kk1 = a1 ? k1 : 0;
    const unsigned int lo0 = 255u - (unsigned)k0, lo1 = 255u - (unsigned)k1;
    const float2 e1_0 = tab[kk0], e1_1 = tab[kk1];          // omega^k  (cos, -sin)
    const float2 e2_0 = tab[2 * kk0], e2_1 = tab[2 * kk1];  // 2k <= 440
    int t3 = 3 * kk0; if (t3 >= WIN) t3 -= WIN; const float2 e3_0 = tab[t3];
    t3 = 3 * kk1; if (t3 >= WIN) t3 -= WIN; const float2 e3_1 = tab[t3];
    double2 Rk0 = TBRg[kk0], Rk1 = TBRg[kk1];               // (cos4th, +sin4th) f64
    if (!a0) { Rk0.x = 0.0; Rk0.y = 0.0; }
    if (!a1) { Rk1.x = 0.0; Rk1.y = 0.0; }

    double S0r, S0i, S1r, S1i;
    // ---- init: f64 Horner, descending 4-sample groups; V <- V*omega^{4k} + D_t ----
    {
        float xa = Xs[440], xb = Xs[441];
        S0r = (double)fmaf(xb, e1_0.x, xa);
        S0i = (double)(xb * e1_0.y);
        S1r = (double)fmaf(xb, e1_1.x, xa);
        S1i = (double)(xb * e1_1.y);
        const float4* Xq = (const float4*)Xs;
#pragma unroll 2
        for (int t = 109; t >= 0; --t) {
            float4 xv = Xq[t];
            float Dr0 = fmaf(xv.w, e3_0.x, fmaf(xv.z, e2_0.x, fmaf(xv.y, e1_0.x, xv.x)));
            float Di0 = fmaf(xv.w, e3_0.y, fmaf(xv.z, e2_0.y, xv.y * e1_0.y));
            double nr = fma(S0i, Rk0.y, fma(S0r, Rk0.x, (double)Dr0));   // Vr*Rr+Vi*Ri+Dr
            double ni = fma(-S0r, Rk0.y, fma(S0i, Rk0.x, (double)Di0));  // Vi*Rr-Vr*Ri+Di
            S0r = nr; S0i = ni;
            float Dr1 = fmaf(xv.w, e3_1.x, fmaf(xv.z, e2_1.x, fmaf(xv.y, e1_1.x, xv.x)));
            float Di1 = fmaf(xv.w, e3_1.y, fmaf(xv.z, e2_1.y, xv.y * e1_1.y));
            nr = fma(S1i, Rk1.y, fma(S1r, Rk1.x, (double)Dr1));
            ni = fma(-S1r, Rk1.y, fma(S1i, Rk1.x, (double)Di1));
            S1r = nr; S1i = ni;
        }
    }
    if (!a0) { S0r = 0.0; S0i = 0.0; }     // inactive: mag stays exactly 0 (Rk=0 keeps it)
    if (!a1) { S1r = 0.0; S1i = 0.0; }

    const float4* Dq = (const float4*)Ds_;
    for (int b = 0; b < 16; ++b) {           // 16 batches x 8 windows
        unsigned long long key[8];
#pragma unroll
        for (int u = 0; u < 8; ++u) {
            if (b | u) {                     // slide into window b*8+u
                float4 d = Dq[b * 8 + u - 1];
                float Dr0 = fmaf(d.w, e3_0.x, fmaf(d.z, e2_0.x, fmaf(d.y, e1_0.x, d.x)));
                float Di0 = fmaf(d.w, e3_0.y, fmaf(d.z, e2_0.y, d.y * e1_0.y));
                double nr = S0r + (double)Dr0;
                double ni = S0i + (double)Di0;
                S0r = fma(nr, Rk0.x, -(ni * Rk0.y));   // nr*Rr - ni*Ri
                S0i = fma(nr, Rk0.y, ni * Rk0.x);      // nr*Ri + ni*Rr
                float Dr1 = fmaf(d.w, e3_1.x, fmaf(d.z, e2_1.x, fmaf(d.y, e1_1.x, d.x)));
                float Di1 = fmaf(d.w, e3_1.y, fmaf(d.z, e2_1.y, d.y * e1_1.y));
                nr = S1r + (double)Dr1;
                ni = S1i + (double)Di1;
                S1r = fma(nr, Rk1.x, -(ni * Rk1.y));
                S1i = fma(nr, Rk1.y, ni * Rk1.x);
            }
            float m0 = (float)(fabs(S0r) + fabs(S0i));   // 1 f64 add (abs mods) + 1 cvt
            float m1 = (float)(fabs(S1r) + fabs(S1i));
            unsigned long long key0 = ((unsigned long long)__float_as_uint(m0) << 32) | lo0;
            unsigned long long key1 = ((unsigned long long)__float_as_uint(m1) << 32) | lo1;
            key[u] = (key1 > key0) ? key1 : key0;        // equal mag -> larger lo = lower k
        }
        // ---- 8 interleaved u64 butterflies, stages 32,16,8,4 ----
#pragma unroll
        for (int s = 0; s < 4; ++s) {
            const int off = 32 >> s;
#pragma unroll
            for (int u = 0; u < 8; ++u) {
                unsigned long long o = shflx64(key[u], off);
                if (o > key[u]) key[u] = o;
            }
        }
        if (lane < 4) {
#pragma unroll
            for (int u = 0; u < 8; ++u) cand[b * 8 + u][wc * 4 + lane] = key[u];
        }
    }
    __syncthreads();
    // ---- merge 8 candidates per window ----
    if (tid < wlen) {
        unsigned long long best = cand[tid][0];
#pragma unroll
        for (int i = 1; i < 8; ++i) {
            unsigned long long c = cand[tid][i];
            if (c > best) best = c;
        }
        a_arr[chunk * LC + tid] = 255 - (int)(best & 255u);
    }
}

// ---------------- Kernel C: per-segment automaton maps, packed (rw+1)<<8 | bin ----------------
__global__ __launch_bounds__(256) void k_maps(const int* __restrict__ a_arr, int n_win,
                                              int L2, int* __restrict__ M0) {
    __shared__ float tf[256];
    __shared__ int ti[256];
    int j = blockIdx.x;
    int wbeg = j * L2;
    int cnt = n_win - wbeg; if (cnt > L2) cnt = L2; if (cnt < 0) cnt = 0;
    for (int i = threadIdx.x; i < cnt; i += 256) {
        int a = a_arr[wbeg + i];
        ti[i] = a; tf[i] = 100.0f * (float)a;
    }
    __syncthreads();
    int b = threadIdx.x;
    if (b < NBINS) {
        float mF = 100.0f * (float)b;
        int bin = b, rw = -1;
        for (int i = 0; i < cnt; ++i) {
            float t = tf[i];
            if (fabsf(mF - t) > mF * 0.0594f) { mF = t; bin = ti[i]; rw = wbeg + i; }
        }
        M0[j * NBINS + b] = ((rw + 1) << 8) | bin;
    }
}

// ---------------- Kernel D: compose 32 consecutive M0 -> M1, LDS-staged ----------------
__global__ __launch_bounds__(256) void k_sm1(const int* __restrict__ M0,
                                             int* __restrict__ M1) {
    __shared__ int sm[32 * NBINS];
    int g = blockIdx.x;
    for (int i = threadIdx.x; i < 32 * NBINS; i += 256) sm[i] = M0[g * 32 * NBINS + i];
    __syncthreads();
    int b = threadIdx.x;
    if (b < NBINS) {
        int bin = b, rw = -1;
        for (int i = 0; i < 32; ++i) {
            int mp = sm[i * NBINS + bin];
            if (mp >> 8) { rw = (mp >> 8) - 1; bin = mp & 255; }
        }
        M1[g * NBINS + b] = ((rw + 1) << 8) | bin;
    }
}

// ---------------- Kernel E: emit flags/freqs/durs + final (fused entry-chain + rescan) ----------------
__global__ __launch_bounds__(256) void k_emit(const int* __restrict__ a_arr,
    const int* __restrict__ M0, const int* __restrict__ M1, int n_win, int L2,
    float* __restrict__ flags, float* __restrict__ freqs, float* __restrict__ durs,
    float* __restrict__ out_final) {
    __shared__ int sm1[NG * NBINS];     // all M1 (28 KB)
    __shared__ float tf[256];
    __shared__ int e0s;
    int j = blockIdx.x;
    int g = j >> 5;
    int wbeg = j * L2;
    int cnt = n_win - wbeg; if (cnt > L2) cnt = L2;
    if (cnt <= 0) return;
    for (int i = threadIdx.x; i < NG * NBINS; i += 256) sm1[i] = M1[i];
    for (int i = threadIdx.x; i < cnt; i += 256) tf[i] = 100.0f * (float)a_arr[wbeg + i];
    __syncthreads();
    if (threadIdx.x == 0) {                      // entry state for this segment
        int bin = 0, rw = -1;
        for (int i = 0; i < g; ++i) {            // E1 chain through LDS-staged M1
            int mp = sm1[i * NBINS + bin];
            if (mp >> 8) { rw = (mp >> 8) - 1; bin = mp & 255; }
        }
        for (int i = g * 32; i < j; ++i) {       // <=31-step M0 chain via L2
            int mp = M0[i * NBINS + bin];
            if (mp >> 8) { rw = (mp >> 8) - 1; bin = mp & 255; }
        }
        e0s = ((rw + 1) << 8) | bin;
    }
    __syncthreads();
    int t = threadIdx.x;
    if (t < cnt) {
        int st = e0s;
        float maxF = 100.0f * (float)(st & 255);
        int rw = (st >> 8) - 1;
        float Ftime = (rw < 0) ? 0.0f : 4.0f * (float)rw;
        for (int i = 0; i < t; ++i) {
            float tv = tf[i];
            if (fabsf(maxF - tv) > maxF * 0.0594f) {
                maxF = tv; Ftime = 4.0f * (float)(wbeg + i);
            }
        }
        int w = wbeg + t;
        float tv = tf[t];
        float iw = 4.0f * (float)w;
        bool cond = fabsf(maxF - tv) > maxF * 0.0594f;
        flags[w] = cond ? 1.0f : 0.0f;
        freqs[w] = maxF;
        durs[w] = (iw - Ftime) * 1000.0f / 44100.0f;
        if (w == n_win - 1) {                    // fold final-state output here
            float fMax = cond ? tv : maxF;
            float fT   = cond ? iw : Ftime;
            out_final[0] = fMax;
            out_final[1] = (iw - fT) * 1000.0f / 44100.0f;
        }
    }
}

extern "C" void kernel_launch(void* const* d_in, const int* in_sizes, int n_in,
                              void* d_out, int out_size, void* d_ws, size_t ws_size,
                              hipStream_t stream) {
    const float* x = (const float*)d_in[0];
    int n = in_sizes[0];
    int n_win = (n - WIN + HOP - 1) / HOP;
    float* out = (float*)d_out;
    char* ws = (char*)d_ws;

    int n_chunks = (n_win + LC - 1) / LC;
    int L2 = (n_win + B2 - 1) / B2;

    // ws layout (~1.95 MB)
    float2*  g_tab = (float2*)(ws + 0);          //   3,536 B
    double2* TBR   = (double2*)(ws + 4096);      //   3,536 B
    int* a_arr     = (int*)(ws + 8192);          // n_chunks*128*4 = 999,936 B
    int* M0        = (int*)(ws + 1008640);       // 1024*221*4 = 905,216 B
    int* M1        = (int*)(ws + 1914112);       //  28,288 B

    k_tables<<<dim3(2), dim3(256), 0, stream>>>(g_tab, TBR);
    k_slide<<<dim3(n_chunks), dim3(128), 0, stream>>>(x, n, n_win, n_chunks,
                                                      g_tab, TBR, a_arr);
    k_maps<<<dim3(B2), dim3(256), 0, stream>>>(a_arr, n_win, L2, M0);
    k_sm1<<<dim3(NG), dim3(256), 0, stream>>>(M0, M1);
    k_emit<<<dim3(B2), dim3(256), 0, stream>>>(a_arr, M0, M1, n_win, L2,
                                               out, out + (size_t)n_win,
                                               out + 2 * (size_t)n_win,
                                               out + 3 * (size_t)n_win);
}